// Round 1
// baseline (82.878 us; speedup 1.0000x reference)
//
#include <hip/hip_runtime.h>
#include <math.h>

namespace {

constexpr int LDSS = 76;  // float stride per 8x8 block region in LDS (bank-conflict-friendly)

// DCT matrix as compile-time constants so the unrolled FMAs use immediates.
struct DctMat {
  float d[8][8];
  constexpr DctMat() : d{} {
    const float CT[17] = {
        1.0f, 0.9807852804032304f, 0.9238795325112867f, 0.8314696123025452f,
        0.7071067811865476f, 0.5555702330196022f, 0.3826834323650898f,
        0.19509032201612825f, 0.0f, -0.19509032201612825f,
        -0.3826834323650898f, -0.5555702330196022f, -0.7071067811865476f,
        -0.8314696123025452f, -0.9238795325112867f, -0.9807852804032304f,
        -1.0f};
    for (int i = 0; i < 8; ++i)
      for (int j = 0; j < 8; ++j) {
        if (i == 0) {
          d[i][j] = 0.35355339059327373f;  // sqrt(1/8)
        } else {
          int m = ((2 * j + 1) * i) % 32;
          if (m > 16) m = 32 - m;
          d[i][j] = 0.5f * CT[m];
        }
      }
  }
};
constexpr DctMat DM{};

// t[i] = sum_j a[j] * D[i][j]   (TRANSPOSED=false)
// t[i] = sum_j a[j] * D[j][i]   (TRANSPOSED=true)
template <bool TRANSPOSED>
__device__ __forceinline__ void mul8(const float (&a)[8], float (&t)[8]) {
#pragma unroll
  for (int i = 0; i < 8; ++i) {
    float s = 0.0f;
#pragma unroll
    for (int j = 0; j < 8; ++j) {
      s = fmaf(a[j], TRANSPOSED ? DM.d[j][i] : DM.d[i][j], s);
    }
    t[i] = s;
  }
}

// In-place 8x8 transpose across the 8 lanes that share one block.
// lp points at this block's wave-private LDS region; r = this lane's row.
__device__ __forceinline__ void transpose8(float (&a)[8], float* lp, int r) {
#pragma unroll
  for (int j = 0; j < 8; ++j) lp[j * 8 + r] = a[j];  // scatter-write transposed
  __syncthreads();
#pragma unroll
  for (int h = 0; h < 2; ++h) {
    float4 v = *reinterpret_cast<const float4*>(lp + r * 8 + h * 4);  // ds_read_b128
    a[h * 4 + 0] = v.x;
    a[h * 4 + 1] = v.y;
    a[h * 4 + 2] = v.z;
    a[h * 4 + 3] = v.w;
  }
}

// Full per-channel pipeline: forward DCT (coef = D*X*D), soft-round quant,
// inverse DCT (rec = D^T*Q*D^T).  a[] in: row r of block; a[] out: row r of rec.
__device__ __forceinline__ void process_chan(float (&a)[8], const float (&qcol)[8],
                                             float* lp, int r) {
  float t[8];
  mul8<true>(a, t);    // T1 = X*D               (lane holds T1 row r)
  transpose8(t, lp, r);  // lane holds T1^T row r
  mul8<false>(t, a);   // a = (T1^T*D^T) row r = coef^T row r = coef[:, r]
#pragma unroll
  for (int i = 0; i < 8; ++i) {
    float qv = qcol[i];
    float x = a[i] * __builtin_amdgcn_rcpf(qv);
    float kc = floorf(x);
    kc = fmaxf(-10.0f, fminf(9.0f, kc));
    // single non-saturated sigmoid term of the soft-round sum
    float arg = 50.0f * (x - kc - 0.5f);
    float e = __expf(-arg);                       // v_exp_f32 path
    float sr = kc + __builtin_amdgcn_rcpf(1.0f + e);
    a[i] = sr * qv;
  }
  mul8<true>(a, t);    // T3 = Q^T*D
  transpose8(t, lp, r);  // lane holds (D^T*Q) row r
  mul8<false>(t, a);   // a = (D^T*Q*D^T) row r = rec row r
}

__device__ __forceinline__ void load8(const float* __restrict__ p, float (&a)[8]) {
  float4 v0 = *reinterpret_cast<const float4*>(p);
  float4 v1 = *reinterpret_cast<const float4*>(p + 4);
  a[0] = v0.x; a[1] = v0.y; a[2] = v0.z; a[3] = v0.w;
  a[4] = v1.x; a[5] = v1.y; a[6] = v1.z; a[7] = v1.w;
}

__device__ __forceinline__ void store8(float* __restrict__ p, const float (&a)[8]) {
  float4 v0 = {a[0], a[1], a[2], a[3]};
  float4 v1 = {a[4], a[5], a[6], a[7]};
  *reinterpret_cast<float4*>(p) = v0;
  *reinterpret_cast<float4*>(p + 4) = v1;
}

__global__ __launch_bounds__(256) void jpeg_kernel(
    const float* __restrict__ img, const float* __restrict__ qy,
    const float* __restrict__ qc, float* __restrict__ out) {
  __shared__ float lds[4 * 8 * LDSS];

  const int tid = threadIdx.x;
  const int wave = tid >> 6;
  const int lane = tid & 63;
  const int blk = lane & 7;   // which of the wave's 8 blocks
  const int r = lane >> 3;    // row within the block

  const int w = blockIdx.x * 4 + wave;  // wave-task id, 0..4095
  const int b = w >> 9;                 // batch (512 tasks per batch)
  const int rr = w & 511;
  const int u = rr >> 3;                // block-row, 0..63
  const int v0 = (rr & 7) << 3;         // first block-col of this wave's strip

  const int row = u * 8 + r;
  const int col = (v0 + blk) * 8;

  float* lp = lds + (wave * 8 + blk) * LDSS;

  const size_t ims = 512 * 512;
  const float* pbase = img + (size_t)b * 3 * ims + (size_t)row * 512 + col;

  float R[8], G[8], B[8];
  load8(pbase, R);
  load8(pbase + ims, G);
  load8(pbase + 2 * ims, B);

  // quant-table columns for this lane (lane's coef column index is r)
  float qycol[8], qccol[8];
#pragma unroll
  for (int i = 0; i < 8; ++i) {
    qycol[i] = fminf(fmaxf(qy[i * 8 + r], 2.0f), 15.0f);
    qccol[i] = fminf(fmaxf(qc[i * 8 + r], 2.0f), 15.0f);
  }

  // clip + RGB -> YCbCr
  float Y[8], Cb[8], Cr[8];
#pragma unroll
  for (int i = 0; i < 8; ++i) {
    float rv = fminf(fmaxf(R[i], 0.0f), 1.0f);
    float gv = fminf(fmaxf(G[i], 0.0f), 1.0f);
    float bv = fminf(fmaxf(B[i], 0.0f), 1.0f);
    Y[i] = 0.299f * rv + 0.587f * gv + 0.114f * bv;
    Cb[i] = -0.168736f * rv - 0.331264f * gv + 0.5f * bv + 0.5f;
    Cr[i] = 0.5f * rv - 0.418688f * gv - 0.081312f * bv + 0.5f;
  }

  process_chan(Y, qycol, lp, r);
  process_chan(Cb, qccol, lp, r);
  process_chan(Cr, qccol, lp, r);

  // YCbCr -> RGB + clip
  float R2[8], G2[8], B2[8];
#pragma unroll
  for (int i = 0; i < 8; ++i) {
    float y2 = Y[i];
    float cb2 = Cb[i] - 0.5f;
    float cr2 = Cr[i] - 0.5f;
    float r2 = y2 + 1.402f * cr2;
    float g2 = y2 - 0.344136f * cb2 - 0.714136f * cr2;
    float b2 = y2 + 1.772f * cb2;
    R2[i] = fminf(fmaxf(r2, 0.0f), 1.0f);
    G2[i] = fminf(fmaxf(g2, 0.0f), 1.0f);
    B2[i] = fminf(fmaxf(b2, 0.0f), 1.0f);
  }

  float* obase = out + (size_t)b * 3 * ims + (size_t)row * 512 + col;
  store8(obase, R2);
  store8(obase + ims, G2);
  store8(obase + 2 * ims, B2);
}

}  // namespace

extern "C" void kernel_launch(void* const* d_in, const int* in_sizes, int n_in,
                              void* d_out, int out_size, void* d_ws, size_t ws_size,
                              hipStream_t stream) {
  const float* img = (const float*)d_in[0];
  const float* qy = (const float*)d_in[1];
  const float* qc = (const float*)d_in[2];
  float* out = (float*)d_out;
  // 8 batches * 64 block-rows * 8 wave-tasks-per-row = 4096 waves = 1024 WGs
  jpeg_kernel<<<dim3(1024), dim3(256), 0, stream>>>(img, qy, qc, out);
}

// Round 2
// 81.983 us; speedup vs baseline: 1.0109x; 1.0109x over previous
//
#include <hip/hip_runtime.h>
#include <math.h>

namespace {

constexpr int LDSS = 76;  // float stride per 8x8 block region in LDS (2-way banks max = free)

// DCT matrix as compile-time constants so the unrolled FMAs use hoisted registers.
struct DctMat {
  float d[8][8];
  constexpr DctMat() : d{} {
    const float CT[17] = {
        1.0f, 0.9807852804032304f, 0.9238795325112867f, 0.8314696123025452f,
        0.7071067811865476f, 0.5555702330196022f, 0.3826834323650898f,
        0.19509032201612825f, 0.0f, -0.19509032201612825f,
        -0.3826834323650898f, -0.5555702330196022f, -0.7071067811865476f,
        -0.8314696123025452f, -0.9238795325112867f, -0.9807852804032304f,
        -1.0f};
    for (int i = 0; i < 8; ++i)
      for (int j = 0; j < 8; ++j) {
        if (i == 0) {
          d[i][j] = 0.35355339059327373f;  // sqrt(1/8)
        } else {
          int m = ((2 * j + 1) * i) % 32;
          if (m > 16) m = 32 - m;
          d[i][j] = 0.5f * CT[m];
        }
      }
  }
};
constexpr DctMat DM{};

// t[i] = sum_j a[j] * D[i][j]   (TRANSPOSED=false)
// t[i] = sum_j a[j] * D[j][i]   (TRANSPOSED=true)
template <bool TRANSPOSED>
__device__ __forceinline__ void mul8(const float (&a)[8], float (&t)[8]) {
#pragma unroll
  for (int i = 0; i < 8; ++i) {
    float s = 0.0f;
#pragma unroll
    for (int j = 0; j < 8; ++j) {
      s = fmaf(a[j], TRANSPOSED ? DM.d[j][i] : DM.d[i][j], s);
    }
    t[i] = s;
  }
}

// Joint 8x8 transpose of all 3 channels across the 8 lanes sharing each block.
// One write burst (24 ds_write_b32) -> one wait -> one read burst (6 ds_read_b128).
// Workgroup is a single wave, so __syncthreads lowers to waitcnt only (s_barrier
// elided for WG size <= wave size).
__device__ __forceinline__ void transpose3(float (&T)[3][8], float* lds, int blk,
                                           int r) {
#pragma unroll
  for (int c = 0; c < 3; ++c) {
    float* lp = lds + (c * 8 + blk) * LDSS;
#pragma unroll
    for (int j = 0; j < 8; ++j) lp[j * 8 + r] = T[c][j];  // scatter-write transposed
  }
  __syncthreads();
#pragma unroll
  for (int c = 0; c < 3; ++c) {
    const float* lp = lds + (c * 8 + blk) * LDSS + r * 8;
    float4 v0 = *reinterpret_cast<const float4*>(lp);      // ds_read_b128
    float4 v1 = *reinterpret_cast<const float4*>(lp + 4);  // ds_read_b128
    T[c][0] = v0.x; T[c][1] = v0.y; T[c][2] = v0.z; T[c][3] = v0.w;
    T[c][4] = v1.x; T[c][5] = v1.y; T[c][6] = v1.z; T[c][7] = v1.w;
  }
  __syncthreads();  // WAR guard before the next write burst (waitcnt only)
}

// Soft-round quantization on 8 coefficient-column elements.
// soft_round(x) ~= kc + sigmoid(50*(x-kc-0.5)), kc = clamp(floor(x),-10,9);
// all other sigmoid terms of the reference's 20-term sum saturate to 0/1
// within 2.6e-11 at TEMP=50.
__device__ __forceinline__ void quant8(float (&a)[8], const float (&q)[8]) {
#pragma unroll
  for (int i = 0; i < 8; ++i) {
    float qv = q[i];
    float x = a[i] * __builtin_amdgcn_rcpf(qv);
    float kc = floorf(x);
    kc = fmaxf(-10.0f, fminf(9.0f, kc));
    float arg = 50.0f * (x - kc - 0.5f);
    float e = __expf(-arg);
    float sr = kc + __builtin_amdgcn_rcpf(1.0f + e);
    a[i] = sr * qv;
  }
}

__device__ __forceinline__ void load8(const float* __restrict__ p, float (&a)[8]) {
  float4 v0 = *reinterpret_cast<const float4*>(p);
  float4 v1 = *reinterpret_cast<const float4*>(p + 4);
  a[0] = v0.x; a[1] = v0.y; a[2] = v0.z; a[3] = v0.w;
  a[4] = v1.x; a[5] = v1.y; a[6] = v1.z; a[7] = v1.w;
}

__device__ __forceinline__ void store8(float* __restrict__ p, const float (&a)[8]) {
  float4 v0 = {a[0], a[1], a[2], a[3]};
  float4 v1 = {a[4], a[5], a[6], a[7]};
  *reinterpret_cast<float4*>(p) = v0;
  *reinterpret_cast<float4*>(p + 4) = v1;
}

__global__ __launch_bounds__(64) void jpeg_kernel(
    const float* __restrict__ img, const float* __restrict__ qy,
    const float* __restrict__ qc, float* __restrict__ out) {
  __shared__ float lds[3 * 8 * LDSS];  // 7.3 KB per (1-wave) workgroup

  const int lane = threadIdx.x;  // 0..63
  const int blk = lane & 7;      // which of the wave's 8 blocks
  const int r = lane >> 3;       // row within the block

  const int w = blockIdx.x;      // wave-task id, 0..4095
  const int b = w >> 9;          // batch (512 tasks per batch)
  const int rr = w & 511;
  const int u = rr >> 3;         // block-row, 0..63
  const int v0 = (rr & 7) << 3;  // first block-col of this wave's strip

  const int row = u * 8 + r;
  const int col = (v0 + blk) * 8;

  const size_t ims = 512 * 512;
  const float* pbase = img + (size_t)b * 3 * ims + (size_t)row * 512 + col;

  float R[8], G[8], B[8];
  load8(pbase, R);
  load8(pbase + ims, G);
  load8(pbase + 2 * ims, B);

  // quant-table columns for this lane (lane's coef column index is r)
  float qycol[8], qccol[8];
#pragma unroll
  for (int i = 0; i < 8; ++i) {
    qycol[i] = fminf(fmaxf(qy[i * 8 + r], 2.0f), 15.0f);
    qccol[i] = fminf(fmaxf(qc[i * 8 + r], 2.0f), 15.0f);
  }

  // clip + RGB -> YCbCr; A[c][j] = row r of channel c's block
  float A[3][8];
#pragma unroll
  for (int i = 0; i < 8; ++i) {
    float rv = fminf(fmaxf(R[i], 0.0f), 1.0f);
    float gv = fminf(fmaxf(G[i], 0.0f), 1.0f);
    float bv = fminf(fmaxf(B[i], 0.0f), 1.0f);
    A[0][i] = 0.299f * rv + 0.587f * gv + 0.114f * bv;
    A[1][i] = -0.168736f * rv - 0.331264f * gv + 0.5f * bv + 0.5f;
    A[2][i] = 0.5f * rv - 0.418688f * gv - 0.081312f * bv + 0.5f;
  }

  // Forward: coef = D * X * D  (computed as ((X*D)^T * D^T)^T, lane holds cols)
  float T[3][8];
#pragma unroll
  for (int c = 0; c < 3; ++c) mul8<true>(A[c], T[c]);  // T = X*D, row r
  transpose3(T, lds, blk, r);                          // T = (X*D)^T, row r
#pragma unroll
  for (int c = 0; c < 3; ++c) mul8<false>(T[c], A[c]); // A = coef column r

  quant8(A[0], qycol);
  quant8(A[1], qccol);
  quant8(A[2], qccol);

  // Inverse: rec = D^T * Q * D^T
#pragma unroll
  for (int c = 0; c < 3; ++c) mul8<true>(A[c], T[c]);
  transpose3(T, lds, blk, r);
#pragma unroll
  for (int c = 0; c < 3; ++c) mul8<false>(T[c], A[c]); // A = rec row r

  // YCbCr -> RGB + clip
  float R2[8], G2[8], B2[8];
#pragma unroll
  for (int i = 0; i < 8; ++i) {
    float y2 = A[0][i];
    float cb2 = A[1][i] - 0.5f;
    float cr2 = A[2][i] - 0.5f;
    float r2 = y2 + 1.402f * cr2;
    float g2 = y2 - 0.344136f * cb2 - 0.714136f * cr2;
    float b2 = y2 + 1.772f * cb2;
    R2[i] = fminf(fmaxf(r2, 0.0f), 1.0f);
    G2[i] = fminf(fmaxf(g2, 0.0f), 1.0f);
    B2[i] = fminf(fmaxf(b2, 0.0f), 1.0f);
  }

  float* obase = out + (size_t)b * 3 * ims + (size_t)row * 512 + col;
  store8(obase, R2);
  store8(obase + ims, G2);
  store8(obase + 2 * ims, B2);
}

}  // namespace

extern "C" void kernel_launch(void* const* d_in, const int* in_sizes, int n_in,
                              void* d_out, int out_size, void* d_ws, size_t ws_size,
                              hipStream_t stream) {
  const float* img = (const float*)d_in[0];
  const float* qy = (const float*)d_in[1];
  const float* qc = (const float*)d_in[2];
  float* out = (float*)d_out;
  // 8 batches * 64 block-rows * 8 strips-per-row = 4096 single-wave workgroups
  jpeg_kernel<<<dim3(4096), dim3(64), 0, stream>>>(img, qy, qc, out);
}